// Round 2
// baseline (1247.975 us; speedup 1.0000x reference)
//
#include <hip/hip_runtime.h>
#include <math.h>

#define NROWS 131072
#define DDIM  512
#define BB    32
#define SS    128
#define KK    8

// ---------------------------------------------------------------------------
// q[b][d] = mean_s query[b][s][d]; also zeroes the write-gate accumulator.
__global__ __launch_bounds__(256) void k_qmean(const float* __restrict__ query,
                                               float* __restrict__ q,
                                               float* __restrict__ pwsum) {
  __shared__ float part[256];
  int b  = blockIdx.x >> 3;            // 32 b
  int dc = blockIdx.x & 7;             // 8 d-chunks of 64
  int t  = threadIdx.x;
  if (blockIdx.x == 0 && t < 32) pwsum[t] = 0.f;   // k_gru atomicAdd target
  int lane = t & 63;
  int p    = t >> 6;                   // s-quarter 0..3
  const float* src = query + (size_t)b * SS * DDIM + (size_t)(p * 32) * DDIM
                   + dc * 64 + lane;
  float s = 0.f;
  #pragma unroll 8
  for (int i = 0; i < 32; ++i) s += src[(size_t)i * DDIM];
  part[t] = s;
  __syncthreads();
  if (t < 64) {
    float tot = part[t] + part[64 + t] + part[128 + t] + part[192 + t];
    q[b * DDIM + dc * 64 + t] = tot * (1.0f / 128.0f);
  }
}

// ---------------------------------------------------------------------------
// FUSED: newmem[r][:] = base[r][:] + A[r][:] @ B
//        scores[b][r] = q[b][:] . newmem[r][:]
// 1 thread = 1 row.  Round-1 lessons applied:
//  * q read from GLOBAL with wave-uniform address -> s_load/L1-broadcast
//    (round-1's LDS-q was ~160us of ds_read_b128 traffic: 16B per 4 FMAs)
//  * newmem written via 34KB double-buffered LDS transpose tile so 4 adjacent
//    lanes cover each 64B line (round-1 row-per-thread stores: WRITE 945MB
//    vs 285MB ideal). Pad 17 floats/row -> 2-way banks (free).
// FMA order identical to round-1 -> newmem & scores bit-identical.
__global__ __launch_bounds__(256, 2) void k_memscores(const float* __restrict__ base,
                                                      const float* __restrict__ A,
                                                      const float* __restrict__ Bm,
                                                      const float* __restrict__ q,
                                                      float* __restrict__ newmem,
                                                      float* __restrict__ scores) {
  __shared__ float buf[2][256][17];           // 34,816 B
  int t = threadIdx.x;
  int r = blockIdx.x * 256 + t;

  // A row -> 16 VGPRs
  const float* Ar = A + (size_t)r * 16;
  float av[16];
  #pragma unroll
  for (int j = 0; j < 4; ++j) {
    float4 a = *(const float4*)(Ar + 4 * j);
    av[4 * j]     = a.x; av[4 * j + 1] = a.y;
    av[4 * j + 2] = a.z; av[4 * j + 3] = a.w;
  }

  float acc[32];
  #pragma unroll
  for (int b = 0; b < 32; ++b) acc[b] = 0.f;

  const float4* brow = (const float4*)(base + (size_t)r * DDIM);
  const float4* qg   = (const float4*)q;      // uniform-address reads
  size_t rowbase = (size_t)blockIdx.x * 256;

  float4 cur0 = brow[0], cur1 = brow[1], cur2 = brow[2], cur3 = brow[3];

  for (int g = 0; g < 32; ++g) {
    // prefetch next group's base (4 float4 in flight per lane)
    int nb = (g < 31) ? 4 * (g + 1) : 0;
    float4 nxt0 = brow[nb];
    float4 nxt1 = brow[nb + 1];
    float4 nxt2 = brow[nb + 2];
    float4 nxt3 = brow[nb + 3];

    // cooperative coalesced store of tile g-1 (written before last barrier)
    if (g > 0) {
      int pg = g - 1, pb = pg & 1;
      #pragma unroll
      for (int it = 0; it < 4; ++it) {
        int s = it * 256 + t;
        int row = s >> 2, pp = s & 3;         // 4 lanes cover one 64B line
        float4 v;
        v.x = buf[pb][row][pp * 4 + 0];
        v.y = buf[pb][row][pp * 4 + 1];
        v.z = buf[pb][row][pp * 4 + 2];
        v.w = buf[pb][row][pp * 4 + 3];
        *(float4*)(newmem + (rowbase + row) * DDIM + pg * 16 + pp * 4) = v;
      }
    }

    #pragma unroll
    for (int j = 0; j < 4; ++j) {
      int d4 = 4 * g + j;
      float4 m = (j == 0) ? cur0 : (j == 1) ? cur1 : (j == 2) ? cur2 : cur3;
      // lora: B slice wave-uniform -> scalar/K$ path
      #pragma unroll
      for (int rr = 0; rr < 16; ++rr) {
        float4 bv = *(const float4*)(Bm + rr * DDIM + 4 * d4);
        m.x += av[rr] * bv.x; m.y += av[rr] * bv.y;
        m.z += av[rr] * bv.z; m.w += av[rr] * bv.w;
      }
      // stage for coalesced write (2-way banks: stride 17 dwords)
      buf[g & 1][t][4 * j + 0] = m.x;
      buf[g & 1][t][4 * j + 1] = m.y;
      buf[g & 1][t][4 * j + 2] = m.z;
      buf[g & 1][t][4 * j + 3] = m.w;
      // scores: q via uniform global load (SGPR/broadcast), 32x reg reuse of m
      #pragma unroll
      for (int b = 0; b < 32; ++b) {
        float4 qv = qg[b * 128 + d4];
        acc[b] += qv.x * m.x + qv.y * m.y + qv.z * m.z + qv.w * m.w;
      }
    }
    cur0 = nxt0; cur1 = nxt1; cur2 = nxt2; cur3 = nxt3;
    __syncthreads();   // orders: writes(g) before reads(g+1); reads(g) before writes(g+1)
  }

  // store last tile (g=31 lives in buf[1])
  #pragma unroll
  for (int it = 0; it < 4; ++it) {
    int s = it * 256 + t;
    int row = s >> 2, pp = s & 3;
    float4 v;
    v.x = buf[1][row][pp * 4 + 0];
    v.y = buf[1][row][pp * 4 + 1];
    v.z = buf[1][row][pp * 4 + 2];
    v.w = buf[1][row][pp * 4 + 3];
    *(float4*)(newmem + (rowbase + row) * DDIM + 31 * 16 + pp * 4) = v;
  }

  #pragma unroll
  for (int b = 0; b < 32; ++b) scores[(size_t)b * NROWS + r] = acc[b];
}

// ---------------------------------------------------------------------------
// top-k comparator: descending by score, ties -> lower index (lax.top_k)
__device__ __forceinline__ void insert8(float (&v)[8], int (&ix)[8], float x, int i) {
  bool better = (x > v[7]) || (x == v[7] && i < ix[7]);
  if (!better) return;
  v[7] = x; ix[7] = i;
  #pragma unroll
  for (int u = 7; u > 0; --u) {
    bool sw = (v[u] > v[u-1]) || (v[u] == v[u-1] && ix[u] < ix[u-1]);
    if (sw) {
      float tv = v[u]; v[u] = v[u-1]; v[u-1] = tv;
      int ti = ix[u]; ix[u] = ix[u-1]; ix[u-1] = ti;
    }
  }
}

// stage 1: grid (32 b x 16 j); block scans 8192 rows -> 8 candidates
__global__ __launch_bounds__(256) void k_topk1(const float* __restrict__ scores,
                                               float* __restrict__ cval,
                                               int* __restrict__ cidx) {
  __shared__ float lval[256][8]; __shared__ int lidx[256][8];
  __shared__ float mval[32][8];  __shared__ int midx[32][8];
  int b = blockIdx.x >> 4, j = blockIdx.x & 15, t = threadIdx.x;
  const float4* s4 = (const float4*)(scores + (size_t)b * NROWS + j * 8192);

  float v[8]; int ix[8];
  #pragma unroll
  for (int e = 0; e < 8; ++e) { v[e] = -1e30f; ix[e] = 0x7fffffff; }
  #pragma unroll
  for (int i = 0; i < 8; ++i) {
    int f4 = i * 256 + t;                     // float4 index in chunk
    float4 x = s4[f4];
    int n0 = j * 8192 + f4 * 4;
    insert8(v, ix, x.x, n0);
    insert8(v, ix, x.y, n0 + 1);
    insert8(v, ix, x.z, n0 + 2);
    insert8(v, ix, x.w, n0 + 3);
  }
  #pragma unroll
  for (int e = 0; e < 8; ++e) { lval[t][e] = v[e]; lidx[t][e] = ix[e]; }
  __syncthreads();

  if (t < 32) {
    float mv[8]; int mi[8];
    #pragma unroll
    for (int e = 0; e < 8; ++e) { mv[e] = -1e30f; mi[e] = 0x7fffffff; }
    for (int u = 0; u < 8; ++u) {
      int src = t * 8 + u;
      #pragma unroll
      for (int e = 0; e < 8; ++e) insert8(mv, mi, lval[src][e], lidx[src][e]);
    }
    #pragma unroll
    for (int e = 0; e < 8; ++e) { mval[t][e] = mv[e]; midx[t][e] = mi[e]; }
  }
  __syncthreads();

  if (t == 0) {
    float mv[8]; int mi[8];
    #pragma unroll
    for (int e = 0; e < 8; ++e) { mv[e] = -1e30f; mi[e] = 0x7fffffff; }
    for (int u = 0; u < 32; ++u)
      #pragma unroll
      for (int e = 0; e < 8; ++e) insert8(mv, mi, mval[u][e], midx[u][e]);
    #pragma unroll
    for (int e = 0; e < 8; ++e) {
      cval[(b * 16 + j) * 8 + e] = mv[e];
      cidx[(b * 16 + j) * 8 + e] = mi[e];
    }
  }
}

// ---------------------------------------------------------------------------
// stage-2 merge (128 candidates -> top-8) fused with gather:
// retrieved[b][k][:] = mem[topidx[b][k]][:]; x[b][:] = sum_k retrieved
__global__ __launch_bounds__(128) void k_gather(const float* __restrict__ mem,
                                                const float* __restrict__ cval,
                                                const int* __restrict__ cidx,
                                                int* __restrict__ topidx,
                                                float* __restrict__ retrieved,
                                                float* __restrict__ x) {
  __shared__ float scv[128]; __shared__ int sci[128];
  __shared__ int stop[8];
  int b = blockIdx.x, t = threadIdx.x;   // t in [0,128)
  scv[t] = cval[b * 128 + t];
  sci[t] = cidx[b * 128 + t];
  __syncthreads();
  if (t == 0) {
    float mv[8]; int mi[8];
    #pragma unroll
    for (int e = 0; e < 8; ++e) { mv[e] = -1e30f; mi[e] = 0x7fffffff; }
    for (int u = 0; u < 128; ++u) insert8(mv, mi, scv[u], sci[u]);
    #pragma unroll
    for (int e = 0; e < 8; ++e) { stop[e] = mi[e]; topidx[b * 8 + e] = mi[e]; }
  }
  __syncthreads();

  float4 xs = make_float4(0.f, 0.f, 0.f, 0.f);
  #pragma unroll
  for (int k = 0; k < 8; ++k) {
    int row = stop[k];
    float4 vv = *(const float4*)(mem + (size_t)row * DDIM + 4 * t);
    *(float4*)(retrieved + (size_t)(b * 8 + k) * DDIM + 4 * t) = vv;
    xs.x += vv.x; xs.y += vv.y; xs.z += vv.z; xs.w += vv.w;
  }
  *(float4*)(x + (size_t)b * DDIM + 4 * t) = xs;
}

// ---------------------------------------------------------------------------
// GRU cell with h0 = 0 (gh = b_hh, w_hh GEMM vanishes).
// 256 blocks (32 b x 8 chunks) x 64 thr: spreads the 3MB wih read over all
// CUs (was 32 blocks -> 32 CUs). Write-gate dot via wave reduce + atomicAdd.
__global__ __launch_bounds__(64) void k_gru(const float* __restrict__ x,
                                            const float* __restrict__ wih,
                                            const float* __restrict__ bih,
                                            const float* __restrict__ bhh,
                                            const float* __restrict__ wgw,
                                            float* __restrict__ hidden,
                                            float* __restrict__ pwsum) {
  int b     = blockIdx.x >> 3;         // 32
  int chunk = blockIdx.x & 7;          // 8
  int t = chunk * 64 + threadIdx.x;    // output index 0..511
  const float* xb = x + b * 512;       // uniform-address reads
  const float* wr = wih + (size_t)t * 512;
  const float* wz = wih + (size_t)(512 + t) * 512;
  const float* wn = wih + (size_t)(1024 + t) * 512;
  float gr = 0.f, gz = 0.f, gn = 0.f;
  #pragma unroll 4
  for (int d4 = 0; d4 < 128; ++d4) {
    float4 xv = *(const float4*)(xb + 4 * d4);
    float4 a = *(const float4*)(wr + 4 * d4);
    float4 c = *(const float4*)(wz + 4 * d4);
    float4 e = *(const float4*)(wn + 4 * d4);
    gr += a.x*xv.x + a.y*xv.y + a.z*xv.z + a.w*xv.w;
    gz += c.x*xv.x + c.y*xv.y + c.z*xv.z + c.w*xv.w;
    gn += e.x*xv.x + e.y*xv.y + e.z*xv.z + e.w*xv.w;
  }
  float r = 1.f / (1.f + expf(-(gr + bih[t]        + bhh[t])));
  float z = 1.f / (1.f + expf(-(gz + bih[512 + t]  + bhh[512 + t])));
  float n = tanhf(gn + bih[1024 + t] + r * bhh[1024 + t]);
  float h = (1.f - z) * n;
  hidden[b * 512 + t] = h;

  float pw = h * wgw[t];
  #pragma unroll
  for (int off = 32; off > 0; off >>= 1) pw += __shfl_down(pw, off, 64);
  if (threadIdx.x == 0) atomicAdd(pwsum + b, pw);
}

// ---------------------------------------------------------------------------
// Sequential-over-batch scatter: new_mem[row] = (1-p)*new_mem[row] + p*q[b]
// p = sigmoid(pwsum[b] + wgb) computed inline.
__global__ __launch_bounds__(256) void k_scatter(float* __restrict__ newmem,
                                                 const int* __restrict__ topidx,
                                                 const float* __restrict__ pwsum,
                                                 const float* __restrict__ wgb,
                                                 const float* __restrict__ q) {
  int t = threadIdx.x;
  int d = blockIdx.x * 64 + (t & 63);    // 8 blocks x 64 d = 512
  int k0 = t >> 6;                       // 0..3
  for (int b = 0; b < 32; ++b) {
    float p = 1.f / (1.f + expf(-(pwsum[b] + wgb[0])));
    float qv = q[b * 512 + d];
    #pragma unroll
    for (int kk = 0; kk < 2; ++kk) {
      int k = k0 + kk * 4;
      int row = topidx[b * 8 + k];
      size_t off = (size_t)row * 512 + d;
      float m = __hip_atomic_load(newmem + off, __ATOMIC_RELAXED,
                                  __HIP_MEMORY_SCOPE_AGENT);
      __hip_atomic_store(newmem + off, (1.f - p) * m + p * qv,
                         __ATOMIC_RELAXED, __HIP_MEMORY_SCOPE_AGENT);
    }
    __syncthreads();
  }
}

// ---------------------------------------------------------------------------
extern "C" void kernel_launch(void* const* d_in, const int* in_sizes, int n_in,
                              void* d_out, int out_size, void* d_ws, size_t ws_size,
                              hipStream_t stream) {
  const float* query = (const float*)d_in[0];
  const float* base  = (const float*)d_in[1];
  const float* lA    = (const float*)d_in[2];
  const float* lB    = (const float*)d_in[3];
  const float* wih   = (const float*)d_in[4];
  // d_in[5] = gru_w_hh: unused (h0 == 0)
  const float* bih   = (const float*)d_in[6];
  const float* bhh   = (const float*)d_in[7];
  const float* wgw   = (const float*)d_in[8];
  const float* wgb   = (const float*)d_in[9];

  float* out = (float*)d_out;
  float* retrieved = out;                    // 32*8*512   = 131072
  float* hidden    = out + 131072;           // 32*512     = 16384
  float* newmem    = out + 147456;           // 131072*512 = 67108864

  float* wq  = (float*)d_ws;                 // 16384
  float* wsc = wq + 16384;                   // 32*131072 = 4194304
  float* wx  = wsc + 4194304;                // 16384
  float* wp  = wx + 16384;                   // 32 (atomicAdd accumulator)
  int*   wti = (int*)(wp + 32);              // 256
  float* wcv = (float*)(wti + 256);          // 32*16*8 = 4096
  int*   wci = (int*)(wcv + 4096);           // 4096

  k_qmean    <<<256, 256, 0, stream>>>(query, wq, wp);
  k_memscores<<<512, 256, 0, stream>>>(base, lA, lB, wq, newmem, wsc);
  k_topk1    <<<512, 256, 0, stream>>>(wsc, wcv, wci);
  k_gather   <<<32,  128, 0, stream>>>(newmem, wcv, wci, wti, retrieved, wx);
  k_gru      <<<256, 64,  0, stream>>>(wx, wih, bih, bhh, wgw, hidden, wp);
  k_scatter  <<<8,   256, 0, stream>>>(newmem, wti, wp, wgb, wq);
}

// Round 3
// 881.663 us; speedup vs baseline: 1.4155x; 1.4155x over previous
//
#include <hip/hip_runtime.h>
#include <math.h>

#define NROWS 131072
#define DDIM  512
#define BB    32
#define SS    128
#define KK    8

// ---------------------------------------------------------------------------
// q[b][d] = mean_s query[b][s][d]; also zeroes the write-gate accumulator.
__global__ __launch_bounds__(256) void k_qmean(const float* __restrict__ query,
                                               float* __restrict__ q,
                                               float* __restrict__ pwsum) {
  __shared__ float part[256];
  int b  = blockIdx.x >> 3;            // 32 b
  int dc = blockIdx.x & 7;             // 8 d-chunks of 64
  int t  = threadIdx.x;
  if (blockIdx.x == 0 && t < 32) pwsum[t] = 0.f;   // k_gru atomicAdd target
  int lane = t & 63;
  int p    = t >> 6;                   // s-quarter 0..3
  const float* src = query + (size_t)b * SS * DDIM + (size_t)(p * 32) * DDIM
                   + dc * 64 + lane;
  float s = 0.f;
  #pragma unroll 8
  for (int i = 0; i < 32; ++i) s += src[(size_t)i * DDIM];
  part[t] = s;
  __syncthreads();
  if (t < 64) {
    float tot = part[t] + part[64 + t] + part[128 + t] + part[192 + t];
    q[b * DDIM + dc * 64 + t] = tot * (1.0f / 128.0f);
  }
}

// ---------------------------------------------------------------------------
// new_mem[n][d] = base[n][d] + sum_r A[n][r]*B[r][d]
// Round-0 layout (column-owning lanes -> 1KB contiguous per wave store inst,
// WRITE_SIZE was exactly ideal). Round-0 defect: ~1 load in flight/wave ->
// 2.3 TB/s latency limit. Fix: explicit 4-row base-load clustering (4KB in
// flight per wave) + 1024 blocks -> 16 waves/CU. FMA order unchanged ->
// newmem bit-identical to round 0.
__global__ __launch_bounds__(256) void k_mem(const float* __restrict__ base,
                                             const float* __restrict__ A,
                                             const float* __restrict__ Bm,
                                             float* __restrict__ newmem) {
  int gt = blockIdx.x * 256 + threadIdx.x;
  int c = gt & 127;            // column group, d = 4c..4c+3
  int stream = gt >> 7;        // 0..2047, 64 rows each
  int row0 = stream * 64;
  int srow0 = __builtin_amdgcn_readfirstlane(row0);   // wave-uniform

  float4 Breg[16];
  #pragma unroll
  for (int r = 0; r < 16; ++r)
    Breg[r] = *(const float4*)(Bm + r * DDIM + 4 * c);

  const float* bp = base   + (size_t)row0 * DDIM + 4 * c;
  float*       np = newmem + (size_t)row0 * DDIM + 4 * c;

  float4 nxt0 = *(const float4*)(bp);
  float4 nxt1 = *(const float4*)(bp + DDIM);
  float4 nxt2 = *(const float4*)(bp + 2 * DDIM);
  float4 nxt3 = *(const float4*)(bp + 3 * DDIM);

  for (int i = 0; i < 64; i += 4) {
    float4 cur0 = nxt0, cur1 = nxt1, cur2 = nxt2, cur3 = nxt3;
    if (i + 4 < 64) {                  // cluster next group's 4 loads
      const float* p = bp + (size_t)(i + 4) * DDIM;
      nxt0 = *(const float4*)(p);
      nxt1 = *(const float4*)(p + DDIM);
      nxt2 = *(const float4*)(p + 2 * DDIM);
      nxt3 = *(const float4*)(p + 3 * DDIM);
    }
    #pragma unroll
    for (int k = 0; k < 4; ++k) {
      const float* Ar = A + (size_t)(srow0 + i + k) * 16;   // uniform -> s_load
      float4 acc = (k == 0) ? cur0 : (k == 1) ? cur1 : (k == 2) ? cur2 : cur3;
      #pragma unroll
      for (int r = 0; r < 16; ++r) {
        float a = Ar[r];
        acc.x += a * Breg[r].x; acc.y += a * Breg[r].y;
        acc.z += a * Breg[r].z; acc.w += a * Breg[r].w;
      }
      *(float4*)(np + (size_t)(i + k) * DDIM) = acc;
    }
  }
}

// ---------------------------------------------------------------------------
// scores[b][n] = sum_d q[b][d] * mem[n][d]
// 256 blocks x 256 thr, 2 rows/thread (r and r+256): halves the q LDS-read
// traffic per FMA (round-1 lesson: 1-row/thread has a ~124us ds_read floor).
// q staged in LDS (NEVER scalar-load a 64KB set: round-2 lesson). 4-deep
// clustered prefetch on both rows. Same per-d4 FMA order -> scores identical.
__global__ __launch_bounds__(256) void k_scores(const float* __restrict__ mem,
                                                const float* __restrict__ q,
                                                float* __restrict__ scores) {
  __shared__ float4 sq[4096];                 // 32 b * 128 d4 = 64 KB
  int t = threadIdx.x;
  const float4* qg = (const float4*)q;
  #pragma unroll
  for (int u = 0; u < 16; ++u) sq[u * 256 + t] = qg[u * 256 + t];
  __syncthreads();

  int r0 = blockIdx.x * 512 + t;              // rows r0 and r0+256
  float acc0[32], acc1[32];
  #pragma unroll
  for (int b = 0; b < 32; ++b) { acc0[b] = 0.f; acc1[b] = 0.f; }

  const float4* m0 = (const float4*)(mem + (size_t)r0 * DDIM);
  const float4* m1 = (const float4*)(mem + (size_t)(r0 + 256) * DDIM);

  float4 a_nxt0 = m0[0], a_nxt1 = m0[1], a_nxt2 = m0[2], a_nxt3 = m0[3];
  float4 b_nxt0 = m1[0], b_nxt1 = m1[1], b_nxt2 = m1[2], b_nxt3 = m1[3];

  for (int g = 0; g < 32; ++g) {
    float4 a0 = a_nxt0, a1 = a_nxt1, a2 = a_nxt2, a3 = a_nxt3;
    float4 c0 = b_nxt0, c1 = b_nxt1, c2 = b_nxt2, c3 = b_nxt3;
    if (g < 31) {                             // cluster 8 next loads
      int nb = 4 * (g + 1);
      a_nxt0 = m0[nb];     a_nxt1 = m0[nb + 1];
      a_nxt2 = m0[nb + 2]; a_nxt3 = m0[nb + 3];
      b_nxt0 = m1[nb];     b_nxt1 = m1[nb + 1];
      b_nxt2 = m1[nb + 2]; b_nxt3 = m1[nb + 3];
    }
    #pragma unroll
    for (int j = 0; j < 4; ++j) {
      int d4 = 4 * g + j;
      float4 x0 = (j == 0) ? a0 : (j == 1) ? a1 : (j == 2) ? a2 : a3;
      float4 x1 = (j == 0) ? c0 : (j == 1) ? c1 : (j == 2) ? c2 : c3;
      #pragma unroll
      for (int b = 0; b < 32; ++b) {
        float4 qv = sq[b * 128 + d4];         // broadcast, feeds 8 FMAs
        acc0[b] += qv.x*x0.x + qv.y*x0.y + qv.z*x0.z + qv.w*x0.w;
        acc1[b] += qv.x*x1.x + qv.y*x1.y + qv.z*x1.z + qv.w*x1.w;
      }
    }
  }
  #pragma unroll
  for (int b = 0; b < 32; ++b) {
    scores[(size_t)b * NROWS + r0]       = acc0[b];
    scores[(size_t)b * NROWS + r0 + 256] = acc1[b];
  }
}

// ---------------------------------------------------------------------------
// top-k comparator: descending by score, ties -> lower index (lax.top_k)
__device__ __forceinline__ void insert8(float (&v)[8], int (&ix)[8], float x, int i) {
  bool better = (x > v[7]) || (x == v[7] && i < ix[7]);
  if (!better) return;
  v[7] = x; ix[7] = i;
  #pragma unroll
  for (int u = 7; u > 0; --u) {
    bool sw = (v[u] > v[u-1]) || (v[u] == v[u-1] && ix[u] < ix[u-1]);
    if (sw) {
      float tv = v[u]; v[u] = v[u-1]; v[u-1] = tv;
      int ti = ix[u]; ix[u] = ix[u-1]; ix[u-1] = ti;
    }
  }
}

// stage 1: grid (32 b x 16 j); block scans 8192 rows -> 8 candidates
__global__ __launch_bounds__(256) void k_topk1(const float* __restrict__ scores,
                                               float* __restrict__ cval,
                                               int* __restrict__ cidx) {
  __shared__ float lval[256][8]; __shared__ int lidx[256][8];
  __shared__ float mval[32][8];  __shared__ int midx[32][8];
  int b = blockIdx.x >> 4, j = blockIdx.x & 15, t = threadIdx.x;
  const float4* s4 = (const float4*)(scores + (size_t)b * NROWS + j * 8192);

  float v[8]; int ix[8];
  #pragma unroll
  for (int e = 0; e < 8; ++e) { v[e] = -1e30f; ix[e] = 0x7fffffff; }
  #pragma unroll
  for (int i = 0; i < 8; ++i) {
    int f4 = i * 256 + t;                     // float4 index in chunk
    float4 x = s4[f4];
    int n0 = j * 8192 + f4 * 4;
    insert8(v, ix, x.x, n0);
    insert8(v, ix, x.y, n0 + 1);
    insert8(v, ix, x.z, n0 + 2);
    insert8(v, ix, x.w, n0 + 3);
  }
  #pragma unroll
  for (int e = 0; e < 8; ++e) { lval[t][e] = v[e]; lidx[t][e] = ix[e]; }
  __syncthreads();

  if (t < 32) {
    float mv[8]; int mi[8];
    #pragma unroll
    for (int e = 0; e < 8; ++e) { mv[e] = -1e30f; mi[e] = 0x7fffffff; }
    for (int u = 0; u < 8; ++u) {
      int src = t * 8 + u;
      #pragma unroll
      for (int e = 0; e < 8; ++e) insert8(mv, mi, lval[src][e], lidx[src][e]);
    }
    #pragma unroll
    for (int e = 0; e < 8; ++e) { mval[t][e] = mv[e]; midx[t][e] = mi[e]; }
  }
  __syncthreads();

  if (t == 0) {
    float mv[8]; int mi[8];
    #pragma unroll
    for (int e = 0; e < 8; ++e) { mv[e] = -1e30f; mi[e] = 0x7fffffff; }
    for (int u = 0; u < 32; ++u)
      #pragma unroll
      for (int e = 0; e < 8; ++e) insert8(mv, mi, mval[u][e], midx[u][e]);
    #pragma unroll
    for (int e = 0; e < 8; ++e) {
      cval[(b * 16 + j) * 8 + e] = mv[e];
      cidx[(b * 16 + j) * 8 + e] = mi[e];
    }
  }
}

// ---------------------------------------------------------------------------
// stage-2 merge (128 candidates -> top-8) fused with gather:
// retrieved[b][k][:] = mem[topidx[b][k]][:]; x[b][:] = sum_k retrieved
__global__ __launch_bounds__(128) void k_gather(const float* __restrict__ mem,
                                                const float* __restrict__ cval,
                                                const int* __restrict__ cidx,
                                                int* __restrict__ topidx,
                                                float* __restrict__ retrieved,
                                                float* __restrict__ x) {
  __shared__ float scv[128]; __shared__ int sci[128];
  __shared__ int stop[8];
  int b = blockIdx.x, t = threadIdx.x;   // t in [0,128)
  scv[t] = cval[b * 128 + t];
  sci[t] = cidx[b * 128 + t];
  __syncthreads();
  if (t == 0) {
    float mv[8]; int mi[8];
    #pragma unroll
    for (int e = 0; e < 8; ++e) { mv[e] = -1e30f; mi[e] = 0x7fffffff; }
    for (int u = 0; u < 128; ++u) insert8(mv, mi, scv[u], sci[u]);
    #pragma unroll
    for (int e = 0; e < 8; ++e) { stop[e] = mi[e]; topidx[b * 8 + e] = mi[e]; }
  }
  __syncthreads();

  float4 xs = make_float4(0.f, 0.f, 0.f, 0.f);
  #pragma unroll
  for (int k = 0; k < 8; ++k) {
    int row = stop[k];
    float4 vv = *(const float4*)(mem + (size_t)row * DDIM + 4 * t);
    *(float4*)(retrieved + (size_t)(b * 8 + k) * DDIM + 4 * t) = vv;
    xs.x += vv.x; xs.y += vv.y; xs.z += vv.z; xs.w += vv.w;
  }
  *(float4*)(x + (size_t)b * DDIM + 4 * t) = xs;
}

// ---------------------------------------------------------------------------
// GRU cell with h0 = 0 (gh = b_hh, w_hh GEMM vanishes).
// 256 blocks (32 b x 8 chunks) x 64 thr. Write-gate dot via wave reduce +
// atomicAdd into pwsum (zeroed by k_qmean).
__global__ __launch_bounds__(64) void k_gru(const float* __restrict__ x,
                                            const float* __restrict__ wih,
                                            const float* __restrict__ bih,
                                            const float* __restrict__ bhh,
                                            const float* __restrict__ wgw,
                                            float* __restrict__ hidden,
                                            float* __restrict__ pwsum) {
  int b     = blockIdx.x >> 3;         // 32
  int chunk = blockIdx.x & 7;          // 8
  int t = chunk * 64 + threadIdx.x;    // output index 0..511
  const float* xb = x + b * 512;       // uniform-address reads
  const float* wr = wih + (size_t)t * 512;
  const float* wz = wih + (size_t)(512 + t) * 512;
  const float* wn = wih + (size_t)(1024 + t) * 512;
  float gr = 0.f, gz = 0.f, gn = 0.f;
  #pragma unroll 4
  for (int d4 = 0; d4 < 128; ++d4) {
    float4 xv = *(const float4*)(xb + 4 * d4);
    float4 a = *(const float4*)(wr + 4 * d4);
    float4 c = *(const float4*)(wz + 4 * d4);
    float4 e = *(const float4*)(wn + 4 * d4);
    gr += a.x*xv.x + a.y*xv.y + a.z*xv.z + a.w*xv.w;
    gz += c.x*xv.x + c.y*xv.y + c.z*xv.z + c.w*xv.w;
    gn += e.x*xv.x + e.y*xv.y + e.z*xv.z + e.w*xv.w;
  }
  float r = 1.f / (1.f + expf(-(gr + bih[t]        + bhh[t])));
  float z = 1.f / (1.f + expf(-(gz + bih[512 + t]  + bhh[512 + t])));
  float n = tanhf(gn + bih[1024 + t] + r * bhh[1024 + t]);
  float h = (1.f - z) * n;
  hidden[b * 512 + t] = h;

  float pw = h * wgw[t];
  #pragma unroll
  for (int off = 32; off > 0; off >>= 1) pw += __shfl_down(pw, off, 64);
  if (threadIdx.x == 0) atomicAdd(pwsum + b, pw);
}

// ---------------------------------------------------------------------------
// Sequential-over-batch scatter: new_mem[row] = (1-p)*new_mem[row] + p*q[b]
// p = sigmoid(pwsum[b] + wgb) computed inline.
__global__ __launch_bounds__(256) void k_scatter(float* __restrict__ newmem,
                                                 const int* __restrict__ topidx,
                                                 const float* __restrict__ pwsum,
                                                 const float* __restrict__ wgb,
                                                 const float* __restrict__ q) {
  int t = threadIdx.x;
  int d = blockIdx.x * 64 + (t & 63);    // 8 blocks x 64 d = 512
  int k0 = t >> 6;                       // 0..3
  for (int b = 0; b < 32; ++b) {
    float p = 1.f / (1.f + expf(-(pwsum[b] + wgb[0])));
    float qv = q[b * 512 + d];
    #pragma unroll
    for (int kk = 0; kk < 2; ++kk) {
      int k = k0 + kk * 4;
      int row = topidx[b * 8 + k];
      size_t off = (size_t)row * 512 + d;
      float m = __hip_atomic_load(newmem + off, __ATOMIC_RELAXED,
                                  __HIP_MEMORY_SCOPE_AGENT);
      __hip_atomic_store(newmem + off, (1.f - p) * m + p * qv,
                         __ATOMIC_RELAXED, __HIP_MEMORY_SCOPE_AGENT);
    }
    __syncthreads();
  }
}

// ---------------------------------------------------------------------------
extern "C" void kernel_launch(void* const* d_in, const int* in_sizes, int n_in,
                              void* d_out, int out_size, void* d_ws, size_t ws_size,
                              hipStream_t stream) {
  const float* query = (const float*)d_in[0];
  const float* base  = (const float*)d_in[1];
  const float* lA    = (const float*)d_in[2];
  const float* lB    = (const float*)d_in[3];
  const float* wih   = (const float*)d_in[4];
  // d_in[5] = gru_w_hh: unused (h0 == 0)
  const float* bih   = (const float*)d_in[6];
  const float* bhh   = (const float*)d_in[7];
  const float* wgw   = (const float*)d_in[8];
  const float* wgb   = (const float*)d_in[9];

  float* out = (float*)d_out;
  float* retrieved = out;                    // 32*8*512   = 131072
  float* hidden    = out + 131072;           // 32*512     = 16384
  float* newmem    = out + 147456;           // 131072*512 = 67108864

  float* wq  = (float*)d_ws;                 // 16384
  float* wsc = wq + 16384;                   // 32*131072 = 4194304
  float* wx  = wsc + 4194304;                // 16384
  float* wp  = wx + 16384;                   // 32 (atomicAdd accumulator)
  int*   wti = (int*)(wp + 32);              // 256
  float* wcv = (float*)(wti + 256);          // 32*16*8 = 4096
  int*   wci = (int*)(wcv + 4096);           // 4096

  k_qmean  <<<256,  256, 0, stream>>>(query, wq, wp);
  k_mem    <<<1024, 256, 0, stream>>>(base, lA, lB, newmem);
  k_scores <<<256,  256, 0, stream>>>(newmem, wq, wsc);
  k_topk1  <<<512,  256, 0, stream>>>(wsc, wcv, wci);
  k_gather <<<32,   128, 0, stream>>>(newmem, wcv, wci, wti, retrieved, wx);
  k_gru    <<<256,  64,  0, stream>>>(wx, wih, bih, bhh, wgw, hidden, wp);
  k_scatter<<<8,    256, 0, stream>>>(newmem, wti, wp, wgb, wq);
}

// Round 4
// 822.350 us; speedup vs baseline: 1.5176x; 1.0721x over previous
//
#include <hip/hip_runtime.h>
#include <math.h>

#define NROWS 131072
#define DDIM  512
#define BB    32
#define SS    128
#define KK    8

// ---------------------------------------------------------------------------
// q[b][d] = mean_s query[b][s][d]; also writes qT[d][b] (for k_scores' scalar
// path) and zeroes the write-gate accumulator.
__global__ __launch_bounds__(256) void k_qmean(const float* __restrict__ query,
                                               float* __restrict__ q,
                                               float* __restrict__ qT,
                                               float* __restrict__ pwsum) {
  __shared__ float part[256];
  int b  = blockIdx.x >> 3;            // 32 b
  int dc = blockIdx.x & 7;             // 8 d-chunks of 64
  int t  = threadIdx.x;
  if (blockIdx.x == 0 && t < 32) pwsum[t] = 0.f;   // k_gru atomicAdd target
  int lane = t & 63;
  int p    = t >> 6;                   // s-quarter 0..3
  const float* src = query + (size_t)b * SS * DDIM + (size_t)(p * 32) * DDIM
                   + dc * 64 + lane;
  float s = 0.f;
  #pragma unroll 8
  for (int i = 0; i < 32; ++i) s += src[(size_t)i * DDIM];
  part[t] = s;
  __syncthreads();
  if (t < 64) {
    float tot = part[t] + part[64 + t] + part[128 + t] + part[192 + t];
    float val = tot * (1.0f / 128.0f);
    int d = dc * 64 + t;
    q[b * DDIM + d]  = val;
    qT[d * 32 + b]   = val;            // 16 KB transposed copy
  }
}

// ---------------------------------------------------------------------------
// new_mem[n][d] = base[n][d] + sum_r A[n][r]*B[r][d]
// Column-owning lanes (ideal coalescing) + 4-row clustered base prefetch
// (4KB in flight/wave; round-0's 1-deep was the 2.3TB/s latency limit).
__global__ __launch_bounds__(256) void k_mem(const float* __restrict__ base,
                                             const float* __restrict__ A,
                                             const float* __restrict__ Bm,
                                             float* __restrict__ newmem) {
  int gt = blockIdx.x * 256 + threadIdx.x;
  int c = gt & 127;            // column group, d = 4c..4c+3
  int stream = gt >> 7;        // 0..2047, 64 rows each
  int row0 = stream * 64;
  int srow0 = __builtin_amdgcn_readfirstlane(row0);   // wave-uniform

  float4 Breg[16];
  #pragma unroll
  for (int r = 0; r < 16; ++r)
    Breg[r] = *(const float4*)(Bm + r * DDIM + 4 * c);

  const float* bp = base   + (size_t)row0 * DDIM + 4 * c;
  float*       np = newmem + (size_t)row0 * DDIM + 4 * c;

  float4 nxt0 = *(const float4*)(bp);
  float4 nxt1 = *(const float4*)(bp + DDIM);
  float4 nxt2 = *(const float4*)(bp + 2 * DDIM);
  float4 nxt3 = *(const float4*)(bp + 3 * DDIM);

  for (int i = 0; i < 64; i += 4) {
    float4 cur0 = nxt0, cur1 = nxt1, cur2 = nxt2, cur3 = nxt3;
    if (i + 4 < 64) {                  // cluster next group's 4 loads
      const float* p = bp + (size_t)(i + 4) * DDIM;
      nxt0 = *(const float4*)(p);
      nxt1 = *(const float4*)(p + DDIM);
      nxt2 = *(const float4*)(p + 2 * DDIM);
      nxt3 = *(const float4*)(p + 3 * DDIM);
    }
    #pragma unroll
    for (int k = 0; k < 4; ++k) {
      const float* Ar = A + (size_t)(srow0 + i + k) * 16;   // uniform -> s_load
      float4 acc = (k == 0) ? cur0 : (k == 1) ? cur1 : (k == 2) ? cur2 : cur3;
      #pragma unroll
      for (int r = 0; r < 16; ++r) {
        float a = Ar[r];
        acc.x += a * Breg[r].x; acc.y += a * Breg[r].y;
        acc.z += a * Breg[r].z; acc.w += a * Breg[r].w;
      }
      *(float4*)(np + (size_t)(i + k) * DDIM) = acc;
    }
  }
}

// ---------------------------------------------------------------------------
// scores[b][n] = sum_d q[b][d] * mem[n][d]
// 1 thread = 1 row; NO LDS. q comes from qT[d][0..31] via wave-uniform loads
// -> SGPRs; the FMA broadcast of q is free (1 SGPR operand per VALU instr).
// Round-3 lesson: 2-row LDS-reuse cost VGPR=256 & 1 wave/SIMD (214us).
// Round-2 lesson inverted: the scalar path is fine when the loop has no LDS
// ops competing on lgkmcnt. Double-buffered q rows by compile-time parity;
// 4-deep clustered mem prefetch. VGPR ~75, 8 waves/CU.
__global__ __launch_bounds__(256) void k_scores(const float* __restrict__ mem,
                                                const float* __restrict__ qT,
                                                float* __restrict__ scores) {
  int t = threadIdx.x;
  int r = blockIdx.x * 256 + t;
  float acc[32];
  #pragma unroll
  for (int b = 0; b < 32; ++b) acc[b] = 0.f;
  const float4* mrow = (const float4*)(mem + (size_t)r * DDIM);

  float4 qA[8], qB[8];                        // q rows d (even) / d (odd)
  #pragma unroll
  for (int u = 0; u < 8; ++u) qA[u] = *(const float4*)(qT + 4 * u);  // d=0

  float4 nxt0 = mrow[0], nxt1 = mrow[1], nxt2 = mrow[2], nxt3 = mrow[3];

  for (int g = 0; g < 32; ++g) {              // 4 d4-groups = 16 d per iter
    float4 c0 = nxt0, c1 = nxt1, c2 = nxt2, c3 = nxt3;
    if (g < 31) {
      nxt0 = mrow[4 * g + 4]; nxt1 = mrow[4 * g + 5];
      nxt2 = mrow[4 * g + 6]; nxt3 = mrow[4 * g + 7];
    }
    #pragma unroll
    for (int j = 0; j < 4; ++j) {
      float4 mv = (j == 0) ? c0 : (j == 1) ? c1 : (j == 2) ? c2 : c3;
      #pragma unroll
      for (int p = 0; p < 4; ++p) {
        int d  = 16 * g + 4 * j + p;          // parity of d == parity of p
        int dn = (d + 1) & 511;
        float mval = (p == 0) ? mv.x : (p == 1) ? mv.y : (p == 2) ? mv.z : mv.w;
        if ((p & 1) == 0) {
          // prefetch next (odd) q row into B, consume A
          #pragma unroll
          for (int u = 0; u < 8; ++u)
            qB[u] = *(const float4*)(qT + dn * 32 + 4 * u);
          #pragma unroll
          for (int b4 = 0; b4 < 8; ++b4) {
            acc[4*b4+0] += qA[b4].x * mval;
            acc[4*b4+1] += qA[b4].y * mval;
            acc[4*b4+2] += qA[b4].z * mval;
            acc[4*b4+3] += qA[b4].w * mval;
          }
        } else {
          #pragma unroll
          for (int u = 0; u < 8; ++u)
            qA[u] = *(const float4*)(qT + dn * 32 + 4 * u);
          #pragma unroll
          for (int b4 = 0; b4 < 8; ++b4) {
            acc[4*b4+0] += qB[b4].x * mval;
            acc[4*b4+1] += qB[b4].y * mval;
            acc[4*b4+2] += qB[b4].z * mval;
            acc[4*b4+3] += qB[b4].w * mval;
          }
        }
      }
    }
  }
  #pragma unroll
  for (int b = 0; b < 32; ++b) scores[(size_t)b * NROWS + r] = acc[b];
}

// ---------------------------------------------------------------------------
// top-k comparator: descending by score, ties -> lower index (lax.top_k)
__device__ __forceinline__ void insert8(float (&v)[8], int (&ix)[8], float x, int i) {
  bool better = (x > v[7]) || (x == v[7] && i < ix[7]);
  if (!better) return;
  v[7] = x; ix[7] = i;
  #pragma unroll
  for (int u = 7; u > 0; --u) {
    bool sw = (v[u] > v[u-1]) || (v[u] == v[u-1] && ix[u] < ix[u-1]);
    if (sw) {
      float tv = v[u]; v[u] = v[u-1]; v[u-1] = tv;
      int ti = ix[u]; ix[u] = ix[u-1]; ix[u-1] = ti;
    }
  }
}

// stage 1: grid (32 b x 16 j); block scans 8192 rows -> 8 candidates
__global__ __launch_bounds__(256) void k_topk1(const float* __restrict__ scores,
                                               float* __restrict__ cval,
                                               int* __restrict__ cidx) {
  __shared__ float lval[256][8]; __shared__ int lidx[256][8];
  __shared__ float mval[32][8];  __shared__ int midx[32][8];
  int b = blockIdx.x >> 4, j = blockIdx.x & 15, t = threadIdx.x;
  const float4* s4 = (const float4*)(scores + (size_t)b * NROWS + j * 8192);

  float v[8]; int ix[8];
  #pragma unroll
  for (int e = 0; e < 8; ++e) { v[e] = -1e30f; ix[e] = 0x7fffffff; }
  #pragma unroll
  for (int i = 0; i < 8; ++i) {
    int f4 = i * 256 + t;                     // float4 index in chunk
    float4 x = s4[f4];
    int n0 = j * 8192 + f4 * 4;
    insert8(v, ix, x.x, n0);
    insert8(v, ix, x.y, n0 + 1);
    insert8(v, ix, x.z, n0 + 2);
    insert8(v, ix, x.w, n0 + 3);
  }
  #pragma unroll
  for (int e = 0; e < 8; ++e) { lval[t][e] = v[e]; lidx[t][e] = ix[e]; }
  __syncthreads();

  if (t < 32) {
    float mv[8]; int mi[8];
    #pragma unroll
    for (int e = 0; e < 8; ++e) { mv[e] = -1e30f; mi[e] = 0x7fffffff; }
    for (int u = 0; u < 8; ++u) {
      int src = t * 8 + u;
      #pragma unroll
      for (int e = 0; e < 8; ++e) insert8(mv, mi, lval[src][e], lidx[src][e]);
    }
    #pragma unroll
    for (int e = 0; e < 8; ++e) { mval[t][e] = mv[e]; midx[t][e] = mi[e]; }
  }
  __syncthreads();

  if (t == 0) {
    float mv[8]; int mi[8];
    #pragma unroll
    for (int e = 0; e < 8; ++e) { mv[e] = -1e30f; mi[e] = 0x7fffffff; }
    for (int u = 0; u < 32; ++u)
      #pragma unroll
      for (int e = 0; e < 8; ++e) insert8(mv, mi, mval[u][e], midx[u][e]);
    #pragma unroll
    for (int e = 0; e < 8; ++e) {
      cval[(b * 16 + j) * 8 + e] = mv[e];
      cidx[(b * 16 + j) * 8 + e] = mi[e];
    }
  }
}

// ---------------------------------------------------------------------------
// stage-2 merge (128 candidates -> top-8) fused with gather:
// retrieved[b][k][:] = mem[topidx[b][k]][:]; x[b][:] = sum_k retrieved
__global__ __launch_bounds__(128) void k_gather(const float* __restrict__ mem,
                                                const float* __restrict__ cval,
                                                const int* __restrict__ cidx,
                                                int* __restrict__ topidx,
                                                float* __restrict__ retrieved,
                                                float* __restrict__ x) {
  __shared__ float scv[128]; __shared__ int sci[128];
  __shared__ int stop[8];
  int b = blockIdx.x, t = threadIdx.x;   // t in [0,128)
  scv[t] = cval[b * 128 + t];
  sci[t] = cidx[b * 128 + t];
  __syncthreads();
  if (t == 0) {
    float mv[8]; int mi[8];
    #pragma unroll
    for (int e = 0; e < 8; ++e) { mv[e] = -1e30f; mi[e] = 0x7fffffff; }
    for (int u = 0; u < 128; ++u) insert8(mv, mi, scv[u], sci[u]);
    #pragma unroll
    for (int e = 0; e < 8; ++e) { stop[e] = mi[e]; topidx[b * 8 + e] = mi[e]; }
  }
  __syncthreads();

  float4 xs = make_float4(0.f, 0.f, 0.f, 0.f);
  #pragma unroll
  for (int k = 0; k < 8; ++k) {
    int row = stop[k];
    float4 vv = *(const float4*)(mem + (size_t)row * DDIM + 4 * t);
    *(float4*)(retrieved + (size_t)(b * 8 + k) * DDIM + 4 * t) = vv;
    xs.x += vv.x; xs.y += vv.y; xs.z += vv.z; xs.w += vv.w;
  }
  *(float4*)(x + (size_t)b * DDIM + 4 * t) = xs;
}

// ---------------------------------------------------------------------------
// GRU cell with h0 = 0 (gh = b_hh, w_hh GEMM vanishes).
// 256 blocks (32 b x 8 chunks) x 64 thr. Write-gate dot via wave reduce +
// atomicAdd into pwsum (zeroed by k_qmean).
__global__ __launch_bounds__(64) void k_gru(const float* __restrict__ x,
                                            const float* __restrict__ wih,
                                            const float* __restrict__ bih,
                                            const float* __restrict__ bhh,
                                            const float* __restrict__ wgw,
                                            float* __restrict__ hidden,
                                            float* __restrict__ pwsum) {
  int b     = blockIdx.x >> 3;         // 32
  int chunk = blockIdx.x & 7;          // 8
  int t = chunk * 64 + threadIdx.x;    // output index 0..511
  const float* xb = x + b * 512;       // uniform-address reads
  const float* wr = wih + (size_t)t * 512;
  const float* wz = wih + (size_t)(512 + t) * 512;
  const float* wn = wih + (size_t)(1024 + t) * 512;
  float gr = 0.f, gz = 0.f, gn = 0.f;
  #pragma unroll 4
  for (int d4 = 0; d4 < 128; ++d4) {
    float4 xv = *(const float4*)(xb + 4 * d4);
    float4 a = *(const float4*)(wr + 4 * d4);
    float4 c = *(const float4*)(wz + 4 * d4);
    float4 e = *(const float4*)(wn + 4 * d4);
    gr += a.x*xv.x + a.y*xv.y + a.z*xv.z + a.w*xv.w;
    gz += c.x*xv.x + c.y*xv.y + c.z*xv.z + c.w*xv.w;
    gn += e.x*xv.x + e.y*xv.y + e.z*xv.z + e.w*xv.w;
  }
  float r = 1.f / (1.f + expf(-(gr + bih[t]        + bhh[t])));
  float z = 1.f / (1.f + expf(-(gz + bih[512 + t]  + bhh[512 + t])));
  float n = tanhf(gn + bih[1024 + t] + r * bhh[1024 + t]);
  float h = (1.f - z) * n;
  hidden[b * 512 + t] = h;

  float pw = h * wgw[t];
  #pragma unroll
  for (int off = 32; off > 0; off >>= 1) pw += __shfl_down(pw, off, 64);
  if (threadIdx.x == 0) atomicAdd(pwsum + b, pw);
}

// ---------------------------------------------------------------------------
// Sequential-over-batch scatter: new_mem[row] = (1-p)*new_mem[row] + p*q[b]
// p = sigmoid(pwsum[b] + wgb) computed inline.
__global__ __launch_bounds__(256) void k_scatter(float* __restrict__ newmem,
                                                 const int* __restrict__ topidx,
                                                 const float* __restrict__ pwsum,
                                                 const float* __restrict__ wgb,
                                                 const float* __restrict__ q) {
  int t = threadIdx.x;
  int d = blockIdx.x * 64 + (t & 63);    // 8 blocks x 64 d = 512
  int k0 = t >> 6;                       // 0..3
  for (int b = 0; b < 32; ++b) {
    float p = 1.f / (1.f + expf(-(pwsum[b] + wgb[0])));
    float qv = q[b * 512 + d];
    #pragma unroll
    for (int kk = 0; kk < 2; ++kk) {
      int k = k0 + kk * 4;
      int row = topidx[b * 8 + k];
      size_t off = (size_t)row * 512 + d;
      float m = __hip_atomic_load(newmem + off, __ATOMIC_RELAXED,
                                  __HIP_MEMORY_SCOPE_AGENT);
      __hip_atomic_store(newmem + off, (1.f - p) * m + p * qv,
                         __ATOMIC_RELAXED, __HIP_MEMORY_SCOPE_AGENT);
    }
    __syncthreads();
  }
}

// ---------------------------------------------------------------------------
extern "C" void kernel_launch(void* const* d_in, const int* in_sizes, int n_in,
                              void* d_out, int out_size, void* d_ws, size_t ws_size,
                              hipStream_t stream) {
  const float* query = (const float*)d_in[0];
  const float* base  = (const float*)d_in[1];
  const float* lA    = (const float*)d_in[2];
  const float* lB    = (const float*)d_in[3];
  const float* wih   = (const float*)d_in[4];
  // d_in[5] = gru_w_hh: unused (h0 == 0)
  const float* bih   = (const float*)d_in[6];
  const float* bhh   = (const float*)d_in[7];
  const float* wgw   = (const float*)d_in[8];
  const float* wgb   = (const float*)d_in[9];

  float* out = (float*)d_out;
  float* retrieved = out;                    // 32*8*512   = 131072
  float* hidden    = out + 131072;           // 32*512     = 16384
  float* newmem    = out + 147456;           // 131072*512 = 67108864

  float* wq  = (float*)d_ws;                 // 16384
  float* wqT = wq + 16384;                   // 16384 (transposed q)
  float* wsc = wqT + 16384;                  // 32*131072 = 4194304
  float* wx  = wsc + 4194304;                // 16384
  float* wp  = wx + 16384;                   // 32 (atomicAdd accumulator)
  int*   wti = (int*)(wp + 32);              // 256
  float* wcv = (float*)(wti + 256);          // 32*16*8 = 4096
  int*   wci = (int*)(wcv + 4096);           // 4096

  k_qmean  <<<256,  256, 0, stream>>>(query, wq, wqT, wp);
  k_mem    <<<1024, 256, 0, stream>>>(base, lA, lB, newmem);
  k_scores <<<512,  256, 0, stream>>>(newmem, wqT, wsc);
  k_topk1  <<<512,  256, 0, stream>>>(wsc, wcv, wci);
  k_gather <<<32,   128, 0, stream>>>(newmem, wcv, wci, wti, retrieved, wx);
  k_gru    <<<256,  64,  0, stream>>>(wx, wih, bih, bhh, wgw, hidden, wp);
  k_scatter<<<8,    256, 0, stream>>>(newmem, wti, wp, wgb, wq);
}